// Round 12
// baseline (96.353 us; speedup 1.0000x reference)
//
#include <hip/hip_runtime.h>
#include <hip/hip_fp16.h>
#include <math.h>

#define NN 1024
#define CC 200
#define AA 256

static constexpr float P_EXP = 0.8f;
static constexpr float Q_EXP = 2.0f;
static constexpr float EPS_C = 0.01f;

typedef __attribute__((ext_vector_type(8))) _Float16 half8;
typedef __attribute__((ext_vector_type(4))) _Float16 half4v;
typedef __attribute__((ext_vector_type(4))) float f32x4;

// ---------------- prep: W->fp16 (208 rows, zero pad) + counts ----------------
__global__ void k_prep(const float* __restrict__ W, const int* __restrict__ lab,
                       _Float16* __restrict__ Whf, float* __restrict__ accv){
  if (blockIdx.x == 52){
    __shared__ int cnt[CC];
    int t = threadIdx.x;
    for (int i = t; i < CC; i += 256) cnt[i] = 0;
    __syncthreads();
    for (int n = t; n < NN; n += 256) atomicAdd(&cnt[lab[n]], 1);
    __syncthreads();
    for (int i = t; i < CC; i += 256) accv[i] = fmaxf((float)cnt[i], 1.0f);
    return;
  }
  int idx = (blockIdx.x * 256 + threadIdx.x) * 4;
  if (idx >= 208 * AA) return;
  float4 w = make_float4(0.f, 0.f, 0.f, 0.f);
  if (idx < CC * AA) w = *(const float4*)(W + idx);
  Whf[idx + 0] = (_Float16)w.x;
  Whf[idx + 1] = (_Float16)w.y;
  Whf[idx + 2] = (_Float16)w.z;
  Whf[idx + 3] = (_Float16)w.w;
}

// ---------------- quadratic form + shift: (a-quarter, l) per block ----------------
// 800 blocks x 256 thr (4 waves) -> ~3 independent blocks/CU for latency hiding.
// Block streams its 64KB CV quarter-slab (4 tiles of 16 rows) through a 2x16KB
// LDS double buffer (global_load_lds, linear dest, source-swizzled), depth-1
// prefetch + __syncthreads (proven R9 schedule). Waves own c-tiles wid+4k.
// MFMA1: M'[a,c]=sum_b CV[a,b]E[c,b]; MFMA2 accumulates diag_c(E[c',a]M'[a,c])
// + this quarter's a-slice of the shift term. Quarters write disjoint tbl slabs.
__global__ __launch_bounds__(256) void k_quad(
    const _Float16* __restrict__ Whf, const float* __restrict__ CV,
    const float* __restrict__ ms, const float* __restrict__ mtg,
    const float* __restrict__ lamp, float* __restrict__ tbl)
{
  const int q    = blockIdx.x;          // a-quarter 0..3
  const int l    = blockIdx.y;
  const int tid  = threadIdx.x;
  const int wid  = tid >> 6;
  const int lane = tid & 63;
  const int lrow = lane & 15;
  const int kgrp = lane >> 4;

  __shared__ float4 cvb[2][16][64];     // 2 x 16KB double buffer
  __shared__ _Float16 dmh[64];          // 2*(mt-ms), this quarter's a-range

  if (tid < 64)
    dmh[tid] = (_Float16)(2.f * (mtg[l * AA + q * 64 + tid] - ms[l * AA + q * 64 + tid]));

  const size_t cvbase = (size_t)l * AA * AA + (size_t)q * 64 * AA;

  // stage tile -> buf: wave wid loads rows {4wid..4wid+3}; LDS linear dest,
  // global source pre-swizzled within the row (slot ^ (row&7)).
  #define STAGE(TILE, BUF) do {                                               \
    _Pragma("unroll")                                                         \
    for (int rr_ = 0; rr_ < 4; ++rr_){                                        \
      int row_ = wid * 4 + rr_;                                               \
      const float* gs_ = CV + cvbase + (size_t)(TILE) * 16 * AA               \
                       + (size_t)row_ * AA + ((lane ^ (row_ & 7)) << 2);      \
      __builtin_amdgcn_global_load_lds(                                       \
        (const __attribute__((address_space(1))) void*)gs_,                   \
        (__attribute__((address_space(3))) void*)&cvb[BUF][row_][0],          \
        16, 0, 0);                                                            \
    }                                                                         \
  } while(0)

  STAGE(0, 0);
  __syncthreads();                      // tile0 + dmh ready

  f32x4 D2[4];
  #pragma unroll
  for (int k = 0; k < 4; ++k) D2[k] = (f32x4){0.f,0.f,0.f,0.f};
  const float lam = lamp[0];

  for (int t = 0; t < 4; ++t){
    if (t + 1 < 4) STAGE(t + 1, (t + 1) & 1);   // issue-early, overlaps compute

    // ---- MFMA1 over this tile: 4 independent c-tile chains per wave ----
    const int buf = t & 1;
    f32x4 a[4];
    #pragma unroll
    for (int k = 0; k < 4; ++k) a[k] = (f32x4){0.f,0.f,0.f,0.f};

    #pragma unroll
    for (int kt = 0; kt < 8; ++kt){
      const int j0 = kt * 8 + kgrp * 2;
      float4 v0 = cvb[buf][lrow][( j0     ) ^ (lrow & 7)];
      float4 v1 = cvb[buf][lrow][( j0 + 1 ) ^ (lrow & 7)];
      half8 cvf;
      cvf[0]=(_Float16)v0.x; cvf[1]=(_Float16)v0.y; cvf[2]=(_Float16)v0.z; cvf[3]=(_Float16)v0.w;
      cvf[4]=(_Float16)v1.x; cvf[5]=(_Float16)v1.y; cvf[6]=(_Float16)v1.z; cvf[7]=(_Float16)v1.w;
      half8 wlv = *(const half8*)(Whf + l * AA + kt * 32 + kgrp * 8);
      #pragma unroll
      for (int k = 0; k < 4; ++k){
        const int ct = wid + k * 4;
        if (ct < 13){
          half8 wcf = *(const half8*)(Whf + (ct * 16 + lrow) * AA + kt * 32 + kgrp * 8);
          a[k] = __builtin_amdgcn_mfma_f32_16x16x32_f16(cvf, wcf - wlv, a[k], 0, 0, 0);
        }
      }
    }

    // ---- MFMA2: contract this tile's a-slice into D2 (+ per-quarter shift) ----
    const int aslg = q * 64 + t * 16 + kgrp * 4;
    half4v wl2 = *(const half4v*)(Whf + l * AA + aslg);
    half4v dmf = *(const half4v*)&dmh[t * 16 + kgrp * 4];
    #pragma unroll
    for (int k = 0; k < 4; ++k){
      const int ct = wid + k * 4;
      if (ct < 13){
        half4v wc2 = *(const half4v*)(Whf + (ct * 16 + lrow) * AA + aslg);
        half4v e2  = wc2 - wl2;
        half4v b2;
        b2[0]=(_Float16)a[k][0]; b2[1]=(_Float16)a[k][1];
        b2[2]=(_Float16)a[k][2]; b2[3]=(_Float16)a[k][3];
        D2[k] = __builtin_amdgcn_mfma_f32_16x16x16f16(e2, b2,  D2[k], 0, 0, 0);
        D2[k] = __builtin_amdgcn_mfma_f32_16x16x16f16(e2, dmf, D2[k], 0, 0, 0);
      }
    }

    __syncthreads();                    // tile t reads done; stage(t+1) drained
  }

  // diag extraction: lane holds D2[m=kgrp*4+jj][n=lrow]; diag at kgrp*4+jj==lrow
  if ((lrow >> 2) == kgrp){
    const int jj = lrow & 3;
    #pragma unroll
    for (int k = 0; k < 4; ++k){
      const int ct = wid + k * 4;
      const int c  = ct * 16 + lrow;
      if (ct < 13 && c < CC){
        float d = (jj == 0) ? D2[k][0] : (jj == 1) ? D2[k][1]
                : (jj == 2) ? D2[k][2] : D2[k][3];
        tbl[(size_t)q * CC * CC + l * CC + c] = 0.5f * lam * d;
      }
    }
  }
  #undef STAGE
}

// ---------------- per-row seesaw loss ----------------
__global__ __launch_bounds__(64) void k_rows(
    const float* __restrict__ ys, const int* __restrict__ lab,
    const float* __restrict__ accv, const float* __restrict__ tbl,
    float* __restrict__ nll)
{
  const int n    = blockIdx.x;
  const int lane = threadIdx.x;
  const int l    = lab[n];
  const float acc_l = accv[l];
  const float log_acc_l = logf(acc_l);

  float z[4];
  float m = -1e30f;
  #pragma unroll
  for (int k = 0; k < 4; k++){
    int cidx = k * 64 + lane;
    float zz = -1e30f;
    if (cidx < CC){
      zz = ys[n * CC + cidx]
         + tbl[             l * CC + cidx] + tbl[    CC * CC + l * CC + cidx]
         + tbl[2 * CC * CC + l * CC + cidx] + tbl[3 * CC * CC + l * CC + cidx];
    }
    z[k] = zz;
    m = fmaxf(m, zz);
  }
  for (int o = 32; o; o >>= 1) m = fmaxf(m, __shfl_xor(m, o));

  float se = 0.f;
  #pragma unroll
  for (int k = 0; k < 4; k++){
    int cidx = k * 64 + lane;
    if (cidx < CC) se += expf(z[k] - m);
  }
  for (int o = 32; o; o >>= 1) se += __shfl_xor(se, o);
  const float L0 = m + logf(se);

  const int kl = l >> 6, ll = l & 63;
  float zsel = (kl == 0) ? z[0] : (kl == 1 ? z[1] : (kl == 2 ? z[2] : z[3]));
  const float zl = __shfl(zsel, ll);
  const float logden = fmaxf(zl - L0, logf(EPS_C));

  float lg[4];
  float m2 = -1e30f;
  #pragma unroll
  for (int k = 0; k < 4; k++){
    int cidx = k * 64 + lane;
    float lz = -1e30f;
    if (cidx < CC){
      lz = z[k];
      if (cidx != l){
        float lratio = (z[k] - L0) - logden;
        float lcomp  = (lratio > 0.f) ? Q_EXP * lratio : 0.f;
        float accc   = accv[cidx];
        float lmit   = (accc < acc_l) ? P_EXP * (logf(accc) - log_acc_l) : 0.f;
        lz += lcomp + lmit;
      }
    }
    lg[k] = lz;
    m2 = fmaxf(m2, lz);
  }
  for (int o = 32; o; o >>= 1) m2 = fmaxf(m2, __shfl_xor(m2, o));
  float se2 = 0.f;
  #pragma unroll
  for (int k = 0; k < 4; k++){
    int cidx = k * 64 + lane;
    if (cidx < CC) se2 += expf(lg[k] - m2);
  }
  for (int o = 32; o; o >>= 1) se2 += __shfl_xor(se2, o);
  const float L1 = m2 + logf(se2);

  if (lane == 0) nll[n] = L1 - zl;
}

// ---------------- mean ----------------
__global__ void k_mean(const float* __restrict__ nll, float* __restrict__ out){
  __shared__ float s[256];
  int t = threadIdx.x;
  float v = 0.f;
  for (int i = t; i < NN; i += 256) v += nll[i];
  s[t] = v; __syncthreads();
  for (int o = 128; o; o >>= 1){ if (t < o) s[t] += s[t + o]; __syncthreads(); }
  if (t == 0) out[0] = s[0] / (float)NN;
}

extern "C" void kernel_launch(void* const* d_in, const int* in_sizes, int n_in,
                              void* d_out, int out_size, void* d_ws, size_t ws_size,
                              hipStream_t stream) {
  const float* W   = (const float*)d_in[0];
  const float* ys  = (const float*)d_in[2];
  const int*   lab = (const int*)  d_in[3];
  const float* lam = (const float*)d_in[4];
  const float* ms  = (const float*)d_in[5];
  const float* mt  = (const float*)d_in[6];
  const float* CV  = (const float*)d_in[7];

  float* ws   = (float*)d_ws;
  float* tbl  = ws;                          // 4 x 40000 (quarter slabs, fully overwritten)
  float* accv = ws + 160000;                 // 256
  float* nll  = ws + 160256;                 // 1024
  _Float16* Whf = (_Float16*)(ws + 161280);  // 208*256 fp16
  float* out  = (float*)d_out;

  k_prep <<<53, 256, 0, stream>>>(W, lab, Whf, accv);
  dim3 gq(4, CC);
  k_quad <<<gq, 256, 0, stream>>>(Whf, CV, ms, mt, lam, tbl);
  k_rows <<<NN, 64, 0, stream>>>(ys, lab, accv, tbl, nll);
  k_mean <<<1, 256, 0, stream>>>(nll, out);
}

// Round 13
// 71.431 us; speedup vs baseline: 1.3489x; 1.3489x over previous
//
#include <hip/hip_runtime.h>
#include <hip/hip_fp16.h>
#include <math.h>

#define NN 1024
#define CC 200
#define AA 256

static constexpr float P_EXP = 0.8f;
static constexpr float Q_EXP = 2.0f;
static constexpr float EPS_C = 0.01f;

typedef __attribute__((ext_vector_type(8))) _Float16 half8;
typedef __attribute__((ext_vector_type(4))) _Float16 half4v;
typedef __attribute__((ext_vector_type(4))) float f32x4;

// ---------------- prep: W->fp16 (208 rows, zero pad) + counts ----------------
__global__ void k_prep(const float* __restrict__ W, const int* __restrict__ lab,
                       _Float16* __restrict__ Whf, float* __restrict__ accv){
  if (blockIdx.x == 52){
    __shared__ int cnt[CC];
    int t = threadIdx.x;
    for (int i = t; i < CC; i += 256) cnt[i] = 0;
    __syncthreads();
    for (int n = t; n < NN; n += 256) atomicAdd(&cnt[lab[n]], 1);
    __syncthreads();
    for (int i = t; i < CC; i += 256) accv[i] = fmaxf((float)cnt[i], 1.0f);
    return;
  }
  int idx = (blockIdx.x * 256 + threadIdx.x) * 4;
  if (idx >= 208 * AA) return;
  float4 w = make_float4(0.f, 0.f, 0.f, 0.f);
  if (idx < CC * AA) w = *(const float4*)(W + idx);
  Whf[idx + 0] = (_Float16)w.x;
  Whf[idx + 1] = (_Float16)w.y;
  Whf[idx + 2] = (_Float16)w.z;
  Whf[idx + 3] = (_Float16)w.w;
}

// ---------------- quadratic form + shift: (b-slice, l) per block ----------------
// 800 blocks x 256 thr (4 waves), ~3 independent blocks/CU. Block (bh,l) owns
// b in [bh*64, bh*64+64): E-frags stay register-resident (8 half8/wave).
// CV b-slice streamed as 8 tiles of 32 a-rows x 64 b (8KB) through a 2-buffer
// LDS ring (global_load_lds, linear dest, source-swizzled slots), depth-1 +
// __syncthreads. MFMA1: M'[a,c] = sum_{b in slice} CV[a,b] E[c,b].
// MFMA2 (per 16-row a-slice): D2 += diag_c( E[c',a] M'[a,c] ), + full-range
// shift term 2dm (bh==0 only; every block iterates ALL a). Disjoint tbl slabs.
__global__ __launch_bounds__(256) void k_quad(
    const _Float16* __restrict__ Whf, const float* __restrict__ CV,
    const float* __restrict__ ms, const float* __restrict__ mtg,
    const float* __restrict__ lamp, float* __restrict__ tbl)
{
  const int bh   = blockIdx.x;          // b-slice 0..3
  const int l    = blockIdx.y;
  const int tid  = threadIdx.x;
  const int wid  = tid >> 6;
  const int lane = tid & 63;
  const int lrow = lane & 15;
  const int kgrp = lane >> 4;
  const int boff = bh * 64;

  __shared__ float cvb[2][32][64];      // 2 x 8KB double buffer
  __shared__ _Float16 dmh[AA];          // 2*(mt-ms), full a-range

  dmh[tid] = (_Float16)(2.f * (mtg[l * AA + tid] - ms[l * AA + tid]));

  // ---- E fragments in registers: wave owns ct = wid + 4k ----
  half8 ef[4][2];
  #pragma unroll
  for (int kt = 0; kt < 2; ++kt){
    half8 wlv = *(const half8*)(Whf + l * AA + boff + kt * 32 + kgrp * 8);
    #pragma unroll
    for (int k = 0; k < 4; ++k){
      const int ct = wid + k * 4;
      const int crow = (ct < 13) ? (ct * 16 + lrow) : 0;
      half8 wcf = *(const half8*)(Whf + crow * AA + boff + kt * 32 + kgrp * 8);
      ef[k][kt] = wcf - wlv;
    }
  }

  const size_t cvbase = (size_t)l * AA * AA + boff;

  // stage tile (32 a-rows x 256B) -> buf: 2 gload_lds per wave (4 rows each),
  // LDS linear dest; global source slot pre-swizzled (slot ^ (row&7)).
  #define STAGE(TILE, BUF) do {                                               \
    _Pragma("unroll")                                                         \
    for (int rr_ = 0; rr_ < 2; ++rr_){                                        \
      int row_  = wid * 8 + rr_ * 4 + (lane >> 4);                            \
      int slot_ = (lane & 15) ^ (row_ & 7);                                   \
      const float* gs_ = CV + cvbase                                          \
        + (size_t)((TILE) * 32 + row_) * AA + slot_ * 4;                      \
      __builtin_amdgcn_global_load_lds(                                       \
        (const __attribute__((address_space(1))) void*)gs_,                   \
        (__attribute__((address_space(3))) void*)&cvb[BUF][wid * 8 + rr_ * 4][0], \
        16, 0, 0);                                                            \
    }                                                                         \
  } while(0)

  STAGE(0, 0);
  __syncthreads();                      // tile0 + dmh ready

  f32x4 D2[4];
  #pragma unroll
  for (int k = 0; k < 4; ++k) D2[k] = (f32x4){0.f,0.f,0.f,0.f};
  const float lam = lamp[0];

  for (int t = 0; t < 8; ++t){
    if (t + 1 < 8) STAGE(t + 1, (t + 1) & 1);   // issue-early, overlaps compute
    const int buf = t & 1;

    #pragma unroll
    for (int s = 0; s < 2; ++s){        // two 16-row a-sub-tiles
      // ---- MFMA1: 4 independent c-tile chains, K = 64 (2 kt) ----
      f32x4 a[4];
      #pragma unroll
      for (int k = 0; k < 4; ++k) a[k] = (f32x4){0.f,0.f,0.f,0.f};

      #pragma unroll
      for (int kt = 0; kt < 2; ++kt){
        const int j0 = kt * 8 + kgrp * 2;
        float4 v0 = *(const float4*)&cvb[buf][s * 16 + lrow][((j0    ) ^ (lrow & 7)) * 4];
        float4 v1 = *(const float4*)&cvb[buf][s * 16 + lrow][((j0 + 1) ^ (lrow & 7)) * 4];
        half8 cvf;
        cvf[0]=(_Float16)v0.x; cvf[1]=(_Float16)v0.y; cvf[2]=(_Float16)v0.z; cvf[3]=(_Float16)v0.w;
        cvf[4]=(_Float16)v1.x; cvf[5]=(_Float16)v1.y; cvf[6]=(_Float16)v1.z; cvf[7]=(_Float16)v1.w;
        #pragma unroll
        for (int k = 0; k < 4; ++k)
          a[k] = __builtin_amdgcn_mfma_f32_16x16x32_f16(cvf, ef[k][kt], a[k], 0, 0, 0);
      }

      // ---- MFMA2: contract this a-slice into D2 (+ shift on bh==0) ----
      const int aslg = t * 32 + s * 16 + kgrp * 4;
      half4v wl2 = *(const half4v*)(Whf + l * AA + aslg);
      half4v dmf = *(const half4v*)&dmh[aslg];
      #pragma unroll
      for (int k = 0; k < 4; ++k){
        const int ct = wid + k * 4;
        if (ct < 13){
          half4v wc2 = *(const half4v*)(Whf + (ct * 16 + lrow) * AA + aslg);
          half4v e2  = wc2 - wl2;
          half4v b2;
          b2[0]=(_Float16)a[k][0]; b2[1]=(_Float16)a[k][1];
          b2[2]=(_Float16)a[k][2]; b2[3]=(_Float16)a[k][3];
          D2[k] = __builtin_amdgcn_mfma_f32_16x16x16f16(e2, b2, D2[k], 0, 0, 0);
          if (bh == 0)
            D2[k] = __builtin_amdgcn_mfma_f32_16x16x16f16(e2, dmf, D2[k], 0, 0, 0);
        }
      }
    }
    __syncthreads();                    // tile t reads done; stage(t+1) drained
  }

  // diag extraction: lane holds D2[m=kgrp*4+jj][n=lrow]; diag at kgrp*4+jj==lrow
  if ((lrow >> 2) == kgrp){
    const int jj = lrow & 3;
    #pragma unroll
    for (int k = 0; k < 4; ++k){
      const int ct = wid + k * 4;
      const int c  = ct * 16 + lrow;
      if (ct < 13 && c < CC){
        float d = (jj == 0) ? D2[k][0] : (jj == 1) ? D2[k][1]
                : (jj == 2) ? D2[k][2] : D2[k][3];
        tbl[(size_t)bh * CC * CC + l * CC + c] = 0.5f * lam * d;
      }
    }
  }
  #undef STAGE
}

// ---------------- per-row seesaw loss ----------------
__global__ __launch_bounds__(64) void k_rows(
    const float* __restrict__ ys, const int* __restrict__ lab,
    const float* __restrict__ accv, const float* __restrict__ tbl,
    float* __restrict__ nll)
{
  const int n    = blockIdx.x;
  const int lane = threadIdx.x;
  const int l    = lab[n];
  const float acc_l = accv[l];
  const float log_acc_l = logf(acc_l);

  float z[4];
  float m = -1e30f;
  #pragma unroll
  for (int k = 0; k < 4; k++){
    int cidx = k * 64 + lane;
    float zz = -1e30f;
    if (cidx < CC){
      zz = ys[n * CC + cidx]
         + tbl[              l * CC + cidx] + tbl[    CC * CC + l * CC + cidx]
         + tbl[2 * CC * CC + l * CC + cidx] + tbl[3 * CC * CC + l * CC + cidx];
    }
    z[k] = zz;
    m = fmaxf(m, zz);
  }
  for (int o = 32; o; o >>= 1) m = fmaxf(m, __shfl_xor(m, o));

  float se = 0.f;
  #pragma unroll
  for (int k = 0; k < 4; k++){
    int cidx = k * 64 + lane;
    if (cidx < CC) se += expf(z[k] - m);
  }
  for (int o = 32; o; o >>= 1) se += __shfl_xor(se, o);
  const float L0 = m + logf(se);

  const int kl = l >> 6, ll = l & 63;
  float zsel = (kl == 0) ? z[0] : (kl == 1 ? z[1] : (kl == 2 ? z[2] : z[3]));
  const float zl = __shfl(zsel, ll);
  const float logden = fmaxf(zl - L0, logf(EPS_C));

  float lg[4];
  float m2 = -1e30f;
  #pragma unroll
  for (int k = 0; k < 4; k++){
    int cidx = k * 64 + lane;
    float lz = -1e30f;
    if (cidx < CC){
      lz = z[k];
      if (cidx != l){
        float lratio = (z[k] - L0) - logden;
        float lcomp  = (lratio > 0.f) ? Q_EXP * lratio : 0.f;
        float accc   = accv[cidx];
        float lmit   = (accc < acc_l) ? P_EXP * (logf(accc) - log_acc_l) : 0.f;
        lz += lcomp + lmit;
      }
    }
    lg[k] = lz;
    m2 = fmaxf(m2, lz);
  }
  for (int o = 32; o; o >>= 1) m2 = fmaxf(m2, __shfl_xor(m2, o));
  float se2 = 0.f;
  #pragma unroll
  for (int k = 0; k < 4; k++){
    int cidx = k * 64 + lane;
    if (cidx < CC) se2 += expf(lg[k] - m2);
  }
  for (int o = 32; o; o >>= 1) se2 += __shfl_xor(se2, o);
  const float L1 = m2 + logf(se2);

  if (lane == 0) nll[n] = L1 - zl;
}

// ---------------- mean ----------------
__global__ void k_mean(const float* __restrict__ nll, float* __restrict__ out){
  __shared__ float s[256];
  int t = threadIdx.x;
  float v = 0.f;
  for (int i = t; i < NN; i += 256) v += nll[i];
  s[t] = v; __syncthreads();
  for (int o = 128; o; o >>= 1){ if (t < o) s[t] += s[t + o]; __syncthreads(); }
  if (t == 0) out[0] = s[0] / (float)NN;
}

extern "C" void kernel_launch(void* const* d_in, const int* in_sizes, int n_in,
                              void* d_out, int out_size, void* d_ws, size_t ws_size,
                              hipStream_t stream) {
  const float* W   = (const float*)d_in[0];
  const float* ys  = (const float*)d_in[2];
  const int*   lab = (const int*)  d_in[3];
  const float* lam = (const float*)d_in[4];
  const float* ms  = (const float*)d_in[5];
  const float* mt  = (const float*)d_in[6];
  const float* CV  = (const float*)d_in[7];

  float* ws   = (float*)d_ws;
  float* tbl  = ws;                          // 4 x 40000 (b-slice slabs, fully overwritten)
  float* accv = ws + 160000;                 // 256
  float* nll  = ws + 160256;                 // 1024
  _Float16* Whf = (_Float16*)(ws + 161280);  // 208*256 fp16
  float* out  = (float*)d_out;

  k_prep <<<53, 256, 0, stream>>>(W, lab, Whf, accv);
  dim3 gq(4, CC);
  k_quad <<<gq, 256, 0, stream>>>(Whf, CV, ms, mt, lam, tbl);
  k_rows <<<NN, 64, 0, stream>>>(ys, lab, accv, tbl, nll);
  k_mean <<<1, 256, 0, stream>>>(nll, out);
}

// Round 14
// 56.810 us; speedup vs baseline: 1.6961x; 1.2574x over previous
//
#include <hip/hip_runtime.h>
#include <hip/hip_fp16.h>
#include <math.h>

#define NN 1024
#define CC 200
#define AA 256

static constexpr float P_EXP = 0.8f;
static constexpr float Q_EXP = 2.0f;
static constexpr float EPS_C = 0.01f;

typedef __attribute__((ext_vector_type(8))) _Float16 half8;
typedef __attribute__((ext_vector_type(4))) _Float16 half4v;
typedef __attribute__((ext_vector_type(4))) float f32x4;

// ---------------- prep: W->fp16 (208 rows, zero pad) + counts ----------------
__global__ void k_prep(const float* __restrict__ W, const int* __restrict__ lab,
                       _Float16* __restrict__ Whf, float* __restrict__ accv){
  if (blockIdx.x == 52){
    __shared__ int cnt[CC];
    int t = threadIdx.x;
    for (int i = t; i < CC; i += 256) cnt[i] = 0;
    __syncthreads();
    for (int n = t; n < NN; n += 256) atomicAdd(&cnt[lab[n]], 1);
    __syncthreads();
    for (int i = t; i < CC; i += 256) accv[i] = fmaxf((float)cnt[i], 1.0f);
    return;
  }
  int idx = (blockIdx.x * 256 + threadIdx.x) * 4;
  if (idx >= 208 * AA) return;
  float4 w = make_float4(0.f, 0.f, 0.f, 0.f);
  if (idx < CC * AA) w = *(const float4*)(W + idx);
  Whf[idx + 0] = (_Float16)w.x;
  Whf[idx + 1] = (_Float16)w.y;
  Whf[idx + 2] = (_Float16)w.z;
  Whf[idx + 3] = (_Float16)w.w;
}

// ---------------- quadratic form + shift: (a-quarter, l) per block ----------------
// 800 blocks x 512 thr (8 waves), ~3 blocks/CU. Block (q,l) streams its
// CONTIGUOUS 64KB CV quarter-slab (4 tiles of 16 rows x 1KB) through a 2x16KB
// LDS double buffer: R9's proven schedule (global_load_lds linear dest,
// source-swizzled, depth-1 prefetch + __syncthreads; no sched_barrier pinning).
// Wave owns c-tiles ct0=wid, ct1=wid+8 (wid<5). MFMA1: M'[a,c]=sum_b CV[a,b]E[c,b];
// MFMA2 accumulates diag_c(E[c',a](M'[a,c] + 2dm[a])) with per-quarter dm slice
// (disjoint across quarters -> added unconditionally). Disjoint tbl slabs.
__global__ __launch_bounds__(512) void k_quad(
    const _Float16* __restrict__ Whf, const float* __restrict__ CV,
    const float* __restrict__ ms, const float* __restrict__ mtg,
    const float* __restrict__ lamp, float* __restrict__ tbl)
{
  const int q    = blockIdx.x;          // a-quarter 0..3
  const int l    = blockIdx.y;
  const int tid  = threadIdx.x;
  const int wid  = tid >> 6;
  const int lane = tid & 63;
  const int lrow = lane & 15;
  const int kgrp = lane >> 4;

  __shared__ float4 cvb[2][16][64];     // 2 x 16KB double buffer
  __shared__ _Float16 dmh[64];          // 2*(mt-ms), this quarter's a-range

  if (tid < 64)
    dmh[tid] = (_Float16)(2.f * (mtg[l * AA + q * 64 + tid] - ms[l * AA + q * 64 + tid]));

  // ---- E fragments: wave owns ct0 = wid, ct1 = wid+8 (compiler may remat) ----
  const int ct0 = wid, ct1 = wid + 8;
  half8 ef0[8], ef1[8];
  #pragma unroll
  for (int kt = 0; kt < 8; ++kt){
    half8 wlv = *(const half8*)(Whf + l * AA + kt * 32 + kgrp * 8);
    half8 wc0 = *(const half8*)(Whf + (ct0 * 16 + lrow) * AA + kt * 32 + kgrp * 8);
    ef0[kt] = wc0 - wlv;
    if (wid < 5){
      half8 wc1 = *(const half8*)(Whf + (ct1 * 16 + lrow) * AA + kt * 32 + kgrp * 8);
      ef1[kt] = wc1 - wlv;
    }
  }

  const size_t cvbase = (size_t)l * AA * AA + (size_t)q * 64 * AA;

  // stage tile -> buf: wave wid loads rows {2wid, 2wid+1}; LDS linear dest,
  // global source pre-swizzled within the row (slot ^ (row&7)).
  #define STAGE(TILE, BUF) do {                                               \
    _Pragma("unroll")                                                         \
    for (int rr_ = 0; rr_ < 2; ++rr_){                                        \
      int row_ = wid * 2 + rr_;                                               \
      const float* gs_ = CV + cvbase + (size_t)(TILE) * 16 * AA               \
                       + (size_t)row_ * AA + ((lane ^ (row_ & 7)) << 2);      \
      __builtin_amdgcn_global_load_lds(                                       \
        (const __attribute__((address_space(1))) void*)gs_,                   \
        (__attribute__((address_space(3))) void*)&cvb[BUF][row_][0],          \
        16, 0, 0);                                                            \
    }                                                                         \
  } while(0)

  STAGE(0, 0);
  __syncthreads();                      // tile0 + dmh ready

  f32x4 D2a = {0.f,0.f,0.f,0.f}, D2b = {0.f,0.f,0.f,0.f};
  const float lam = lamp[0];

  for (int t = 0; t < 4; ++t){
    if (t + 1 < 4) STAGE(t + 1, (t + 1) & 1);   // issue-early, overlaps compute

    // ---- MFMA1 over this tile ----
    const int buf = t & 1;
    f32x4 a0 = {0.f,0.f,0.f,0.f}, a1 = {0.f,0.f,0.f,0.f};
    #pragma unroll
    for (int kt = 0; kt < 8; ++kt){
      const int j0 = kt * 8 + kgrp * 2;
      float4 v0 = cvb[buf][lrow][( j0     ) ^ (lrow & 7)];
      float4 v1 = cvb[buf][lrow][( j0 + 1 ) ^ (lrow & 7)];
      half8 cvf;
      cvf[0]=(_Float16)v0.x; cvf[1]=(_Float16)v0.y; cvf[2]=(_Float16)v0.z; cvf[3]=(_Float16)v0.w;
      cvf[4]=(_Float16)v1.x; cvf[5]=(_Float16)v1.y; cvf[6]=(_Float16)v1.z; cvf[7]=(_Float16)v1.w;
      a0 = __builtin_amdgcn_mfma_f32_16x16x32_f16(cvf, ef0[kt], a0, 0, 0, 0);
      if (wid < 5)
        a1 = __builtin_amdgcn_mfma_f32_16x16x32_f16(cvf, ef1[kt], a1, 0, 0, 0);
    }

    // ---- MFMA2: contract this tile's a-slice into D2 (+ quarter's shift) ----
    const int aslg = q * 64 + t * 16 + kgrp * 4;
    half4v wl2 = *(const half4v*)(Whf + l * AA + aslg);
    half4v dmf = *(const half4v*)&dmh[t * 16 + kgrp * 4];
    {
      half4v wc2 = *(const half4v*)(Whf + (ct0 * 16 + lrow) * AA + aslg);
      half4v e2  = wc2 - wl2;
      half4v b2;
      b2[0]=(_Float16)a0[0]; b2[1]=(_Float16)a0[1]; b2[2]=(_Float16)a0[2]; b2[3]=(_Float16)a0[3];
      D2a = __builtin_amdgcn_mfma_f32_16x16x16f16(e2, b2,  D2a, 0, 0, 0);
      D2a = __builtin_amdgcn_mfma_f32_16x16x16f16(e2, dmf, D2a, 0, 0, 0);
    }
    if (wid < 5){
      half4v wc2 = *(const half4v*)(Whf + (ct1 * 16 + lrow) * AA + aslg);
      half4v e2  = wc2 - wl2;
      half4v b2;
      b2[0]=(_Float16)a1[0]; b2[1]=(_Float16)a1[1]; b2[2]=(_Float16)a1[2]; b2[3]=(_Float16)a1[3];
      D2b = __builtin_amdgcn_mfma_f32_16x16x16f16(e2, b2,  D2b, 0, 0, 0);
      D2b = __builtin_amdgcn_mfma_f32_16x16x16f16(e2, dmf, D2b, 0, 0, 0);
    }

    __syncthreads();                    // tile t reads done; stage(t+1) drained
  }

  // diag extraction: lane holds D2[m=kgrp*4+jj][n=lrow]; diag at kgrp*4+jj==lrow
  if ((lrow >> 2) == kgrp){
    const int jj = lrow & 3;
    const int c0 = ct0 * 16 + lrow;
    float d0 = (jj == 0) ? D2a[0] : (jj == 1) ? D2a[1] : (jj == 2) ? D2a[2] : D2a[3];
    if (c0 < CC) tbl[(size_t)q * CC * CC + l * CC + c0] = 0.5f * lam * d0;
    if (wid < 5){
      const int c1 = ct1 * 16 + lrow;
      float d1 = (jj == 0) ? D2b[0] : (jj == 1) ? D2b[1] : (jj == 2) ? D2b[2] : D2b[3];
      if (c1 < CC) tbl[(size_t)q * CC * CC + l * CC + c1] = 0.5f * lam * d1;
    }
  }
  #undef STAGE
}

// ---------------- per-row seesaw loss ----------------
__global__ __launch_bounds__(64) void k_rows(
    const float* __restrict__ ys, const int* __restrict__ lab,
    const float* __restrict__ accv, const float* __restrict__ tbl,
    float* __restrict__ nll)
{
  const int n    = blockIdx.x;
  const int lane = threadIdx.x;
  const int l    = lab[n];
  const float acc_l = accv[l];
  const float log_acc_l = logf(acc_l);

  float z[4];
  float m = -1e30f;
  #pragma unroll
  for (int k = 0; k < 4; k++){
    int cidx = k * 64 + lane;
    float zz = -1e30f;
    if (cidx < CC){
      zz = ys[n * CC + cidx]
         + tbl[              l * CC + cidx] + tbl[    CC * CC + l * CC + cidx]
         + tbl[2 * CC * CC + l * CC + cidx] + tbl[3 * CC * CC + l * CC + cidx];
    }
    z[k] = zz;
    m = fmaxf(m, zz);
  }
  for (int o = 32; o; o >>= 1) m = fmaxf(m, __shfl_xor(m, o));

  float se = 0.f;
  #pragma unroll
  for (int k = 0; k < 4; k++){
    int cidx = k * 64 + lane;
    if (cidx < CC) se += expf(z[k] - m);
  }
  for (int o = 32; o; o >>= 1) se += __shfl_xor(se, o);
  const float L0 = m + logf(se);

  const int kl = l >> 6, ll = l & 63;
  float zsel = (kl == 0) ? z[0] : (kl == 1 ? z[1] : (kl == 2 ? z[2] : z[3]));
  const float zl = __shfl(zsel, ll);
  const float logden = fmaxf(zl - L0, logf(EPS_C));

  float lg[4];
  float m2 = -1e30f;
  #pragma unroll
  for (int k = 0; k < 4; k++){
    int cidx = k * 64 + lane;
    float lz = -1e30f;
    if (cidx < CC){
      lz = z[k];
      if (cidx != l){
        float lratio = (z[k] - L0) - logden;
        float lcomp  = (lratio > 0.f) ? Q_EXP * lratio : 0.f;
        float accc   = accv[cidx];
        float lmit   = (accc < acc_l) ? P_EXP * (logf(accc) - log_acc_l) : 0.f;
        lz += lcomp + lmit;
      }
    }
    lg[k] = lz;
    m2 = fmaxf(m2, lz);
  }
  for (int o = 32; o; o >>= 1) m2 = fmaxf(m2, __shfl_xor(m2, o));
  float se2 = 0.f;
  #pragma unroll
  for (int k = 0; k < 4; k++){
    int cidx = k * 64 + lane;
    if (cidx < CC) se2 += expf(lg[k] - m2);
  }
  for (int o = 32; o; o >>= 1) se2 += __shfl_xor(se2, o);
  const float L1 = m2 + logf(se2);

  if (lane == 0) nll[n] = L1 - zl;
}

// ---------------- mean ----------------
__global__ void k_mean(const float* __restrict__ nll, float* __restrict__ out){
  __shared__ float s[256];
  int t = threadIdx.x;
  float v = 0.f;
  for (int i = t; i < NN; i += 256) v += nll[i];
  s[t] = v; __syncthreads();
  for (int o = 128; o; o >>= 1){ if (t < o) s[t] += s[t + o]; __syncthreads(); }
  if (t == 0) out[0] = s[0] / (float)NN;
}

extern "C" void kernel_launch(void* const* d_in, const int* in_sizes, int n_in,
                              void* d_out, int out_size, void* d_ws, size_t ws_size,
                              hipStream_t stream) {
  const float* W   = (const float*)d_in[0];
  const float* ys  = (const float*)d_in[2];
  const int*   lab = (const int*)  d_in[3];
  const float* lam = (const float*)d_in[4];
  const float* ms  = (const float*)d_in[5];
  const float* mt  = (const float*)d_in[6];
  const float* CV  = (const float*)d_in[7];

  float* ws   = (float*)d_ws;
  float* tbl  = ws;                          // 4 x 40000 (quarter slabs, fully overwritten)
  float* accv = ws + 160000;                 // 256
  float* nll  = ws + 160256;                 // 1024
  _Float16* Whf = (_Float16*)(ws + 161280);  // 208*256 fp16
  float* out  = (float*)d_out;

  k_prep <<<53, 256, 0, stream>>>(W, lab, Whf, accv);
  dim3 gq(4, CC);
  k_quad <<<gq, 512, 0, stream>>>(Whf, CV, ms, mt, lam, tbl);
  k_rows <<<NN, 64, 0, stream>>>(ys, lab, accv, tbl, nll);
  k_mean <<<1, 256, 0, stream>>>(nll, out);
}

// Round 15
// 54.129 us; speedup vs baseline: 1.7801x; 1.0495x over previous
//
#include <hip/hip_runtime.h>
#include <hip/hip_fp16.h>
#include <math.h>

#define NN 1024
#define CC 200
#define AA 256

static constexpr float P_EXP = 0.8f;
static constexpr float Q_EXP = 2.0f;
static constexpr float EPS_C = 0.01f;

typedef __attribute__((ext_vector_type(8))) _Float16 half8;
typedef __attribute__((ext_vector_type(4))) _Float16 half4v;
typedef __attribute__((ext_vector_type(4))) float f32x4;

// ---------------- prep: W->fp16 (208 rows, zero pad) + counts ----------------
__global__ void k_prep(const float* __restrict__ W, const int* __restrict__ lab,
                       _Float16* __restrict__ Whf, float* __restrict__ accv){
  if (blockIdx.x == 52){
    __shared__ int cnt[CC];
    int t = threadIdx.x;
    for (int i = t; i < CC; i += 256) cnt[i] = 0;
    __syncthreads();
    for (int n = t; n < NN; n += 256) atomicAdd(&cnt[lab[n]], 1);
    __syncthreads();
    for (int i = t; i < CC; i += 256) accv[i] = fmaxf((float)cnt[i], 1.0f);
    return;
  }
  int idx = (blockIdx.x * 256 + threadIdx.x) * 4;
  if (idx >= 208 * AA) return;
  float4 w = make_float4(0.f, 0.f, 0.f, 0.f);
  if (idx < CC * AA) w = *(const float4*)(W + idx);
  Whf[idx + 0] = (_Float16)w.x;
  Whf[idx + 1] = (_Float16)w.y;
  Whf[idx + 2] = (_Float16)w.z;
  Whf[idx + 3] = (_Float16)w.w;
}

// ---------------- quadratic form + shift: (a-quarter, l) per block ----------------
// 800 blocks x 512 thr. SINGLE-SHOT staging: the whole 64KB fp32 quarter-slab is
// loaded in one burst (8 dwordx4 in flight per thread = 64KB/block in flight),
// converted to fp16 in registers, written swizzled to a 32KB LDS buffer, ONE
// __syncthreads, then all 4 a-tiles computed barrier-free from LDS.
// MFMA1: M'[a,c]=sum_b CV[a,b]E[c,b]; MFMA2: D2 += diag_c(E[c',a](M'+2dm)) with
// per-quarter dm slice (disjoint -> unconditional). Disjoint tbl slabs.
__global__ __launch_bounds__(512) void k_quad(
    const _Float16* __restrict__ Whf, const float* __restrict__ CV,
    const float* __restrict__ ms, const float* __restrict__ mtg,
    const float* __restrict__ lamp, float* __restrict__ tbl)
{
  const int q    = blockIdx.x;          // a-quarter 0..3
  const int l    = blockIdx.y;
  const int tid  = threadIdx.x;
  const int wid  = tid >> 6;
  const int lane = tid & 63;
  const int lrow = lane & 15;
  const int kgrp = lane >> 4;

  __shared__ _Float16 cvh[64][256];     // 32KB fp16 slab (swizzled 16B slots)

  // ---- burst-load the whole quarter slab (coalesced, 8 loads in flight) ----
  const float* src = CV + (size_t)l * AA * AA + (size_t)q * 64 * AA;
  float4 v[8];
  #pragma unroll
  for (int i = 0; i < 8; ++i)
    v[i] = *(const float4*)(src + (size_t)(i * 512 + tid) * 4);

  // ---- E fragments: wave owns ct0 = wid, ct1 = wid+8 ----
  const int ct0 = wid, ct1 = wid + 8;
  half8 ef0[8], ef1[8];
  #pragma unroll
  for (int kt = 0; kt < 8; ++kt){
    half8 wlv = *(const half8*)(Whf + l * AA + kt * 32 + kgrp * 8);
    half8 wc0 = *(const half8*)(Whf + (ct0 * 16 + lrow) * AA + kt * 32 + kgrp * 8);
    ef0[kt] = wc0 - wlv;
    if (wid < 5){
      half8 wc1 = *(const half8*)(Whf + (ct1 * 16 + lrow) * AA + kt * 32 + kgrp * 8);
      ef1[kt] = wc1 - wlv;
    }
  }

  // ---- cvt + swizzled fp16 LDS write (write XOR == read XOR) ----
  #pragma unroll
  for (int i = 0; i < 8; ++i){
    int f    = i * 512 + tid;           // 16B fp32 chunk index in slab
    int row  = f >> 6;                  // 0..63
    int c16  = f & 63;                  // fp32 chunk in row
    int slot = (c16 >> 1) ^ (row & 7);  // fp16 16B slot, swizzled
    half4v h;
    h[0] = (_Float16)v[i].x; h[1] = (_Float16)v[i].y;
    h[2] = (_Float16)v[i].z; h[3] = (_Float16)v[i].w;
    *(half4v*)(&cvh[row][0] + slot * 8 + (c16 & 1) * 4) = h;
  }
  __syncthreads();                      // slab ready; only barrier in kernel

  f32x4 D2a = {0.f,0.f,0.f,0.f}, D2b = {0.f,0.f,0.f,0.f};
  const float lam = lamp[0];

  #pragma unroll
  for (int t = 0; t < 4; ++t){
    // ---- MFMA1 over tile t (fp16 LDS reads: one b128 per kt) ----
    f32x4 a0 = {0.f,0.f,0.f,0.f}, a1 = {0.f,0.f,0.f,0.f};
    const int row = t * 16 + lrow;
    #pragma unroll
    for (int kt = 0; kt < 8; ++kt){
      half8 cvf = *(const half8*)(&cvh[row][0] + (((kt * 4 + kgrp) ^ (row & 7)) * 8));
      a0 = __builtin_amdgcn_mfma_f32_16x16x32_f16(cvf, ef0[kt], a0, 0, 0, 0);
      if (wid < 5)
        a1 = __builtin_amdgcn_mfma_f32_16x16x32_f16(cvf, ef1[kt], a1, 0, 0, 0);
    }

    // ---- MFMA2: contract tile's a-slice into D2 (+ quarter's shift) ----
    const int aslg = q * 64 + t * 16 + kgrp * 4;
    half4v wl2 = *(const half4v*)(Whf + l * AA + aslg);
    float4 dmt = *(const float4*)(mtg + l * AA + aslg);
    float4 dms = *(const float4*)(ms  + l * AA + aslg);
    half4v dmf;
    dmf[0] = (_Float16)(2.f * (dmt.x - dms.x));
    dmf[1] = (_Float16)(2.f * (dmt.y - dms.y));
    dmf[2] = (_Float16)(2.f * (dmt.z - dms.z));
    dmf[3] = (_Float16)(2.f * (dmt.w - dms.w));
    {
      half4v wc2 = *(const half4v*)(Whf + (ct0 * 16 + lrow) * AA + aslg);
      half4v e2  = wc2 - wl2;
      half4v b2;
      b2[0]=(_Float16)a0[0]; b2[1]=(_Float16)a0[1]; b2[2]=(_Float16)a0[2]; b2[3]=(_Float16)a0[3];
      D2a = __builtin_amdgcn_mfma_f32_16x16x16f16(e2, b2,  D2a, 0, 0, 0);
      D2a = __builtin_amdgcn_mfma_f32_16x16x16f16(e2, dmf, D2a, 0, 0, 0);
    }
    if (wid < 5){
      half4v wc2 = *(const half4v*)(Whf + (ct1 * 16 + lrow) * AA + aslg);
      half4v e2  = wc2 - wl2;
      half4v b2;
      b2[0]=(_Float16)a1[0]; b2[1]=(_Float16)a1[1]; b2[2]=(_Float16)a1[2]; b2[3]=(_Float16)a1[3];
      D2b = __builtin_amdgcn_mfma_f32_16x16x16f16(e2, b2,  D2b, 0, 0, 0);
      D2b = __builtin_amdgcn_mfma_f32_16x16x16f16(e2, dmf, D2b, 0, 0, 0);
    }
  }

  // diag extraction: lane holds D2[m=kgrp*4+jj][n=lrow]; diag at kgrp*4+jj==lrow
  if ((lrow >> 2) == kgrp){
    const int jj = lrow & 3;
    const int c0 = ct0 * 16 + lrow;
    float d0 = (jj == 0) ? D2a[0] : (jj == 1) ? D2a[1] : (jj == 2) ? D2a[2] : D2a[3];
    if (c0 < CC) tbl[(size_t)q * CC * CC + l * CC + c0] = 0.5f * lam * d0;
    if (wid < 5){
      const int c1 = ct1 * 16 + lrow;
      float d1 = (jj == 0) ? D2b[0] : (jj == 1) ? D2b[1] : (jj == 2) ? D2b[2] : D2b[3];
      if (c1 < CC) tbl[(size_t)q * CC * CC + l * CC + c1] = 0.5f * lam * d1;
    }
  }
}

// ---------------- per-row seesaw loss ----------------
__global__ __launch_bounds__(64) void k_rows(
    const float* __restrict__ ys, const int* __restrict__ lab,
    const float* __restrict__ accv, const float* __restrict__ tbl,
    float* __restrict__ nll)
{
  const int n    = blockIdx.x;
  const int lane = threadIdx.x;
  const int l    = lab[n];
  const float acc_l = accv[l];
  const float log_acc_l = logf(acc_l);

  float z[4];
  float m = -1e30f;
  #pragma unroll
  for (int k = 0; k < 4; k++){
    int cidx = k * 64 + lane;
    float zz = -1e30f;
    if (cidx < CC){
      zz = ys[n * CC + cidx]
         + tbl[              l * CC + cidx] + tbl[    CC * CC + l * CC + cidx]
         + tbl[2 * CC * CC + l * CC + cidx] + tbl[3 * CC * CC + l * CC + cidx];
    }
    z[k] = zz;
    m = fmaxf(m, zz);
  }
  for (int o = 32; o; o >>= 1) m = fmaxf(m, __shfl_xor(m, o));

  float se = 0.f;
  #pragma unroll
  for (int k = 0; k < 4; k++){
    int cidx = k * 64 + lane;
    if (cidx < CC) se += expf(z[k] - m);
  }
  for (int o = 32; o; o >>= 1) se += __shfl_xor(se, o);
  const float L0 = m + logf(se);

  const int kl = l >> 6, ll = l & 63;
  float zsel = (kl == 0) ? z[0] : (kl == 1 ? z[1] : (kl == 2 ? z[2] : z[3]));
  const float zl = __shfl(zsel, ll);
  const float logden = fmaxf(zl - L0, logf(EPS_C));

  float lg[4];
  float m2 = -1e30f;
  #pragma unroll
  for (int k = 0; k < 4; k++){
    int cidx = k * 64 + lane;
    float lz = -1e30f;
    if (cidx < CC){
      lz = z[k];
      if (cidx != l){
        float lratio = (z[k] - L0) - logden;
        float lcomp  = (lratio > 0.f) ? Q_EXP * lratio : 0.f;
        float accc   = accv[cidx];
        float lmit   = (accc < acc_l) ? P_EXP * (logf(accc) - log_acc_l) : 0.f;
        lz += lcomp + lmit;
      }
    }
    lg[k] = lz;
    m2 = fmaxf(m2, lz);
  }
  for (int o = 32; o; o >>= 1) m2 = fmaxf(m2, __shfl_xor(m2, o));
  float se2 = 0.f;
  #pragma unroll
  for (int k = 0; k < 4; k++){
    int cidx = k * 64 + lane;
    if (cidx < CC) se2 += expf(lg[k] - m2);
  }
  for (int o = 32; o; o >>= 1) se2 += __shfl_xor(se2, o);
  const float L1 = m2 + logf(se2);

  if (lane == 0) nll[n] = L1 - zl;
}

// ---------------- mean ----------------
__global__ void k_mean(const float* __restrict__ nll, float* __restrict__ out){
  __shared__ float s[256];
  int t = threadIdx.x;
  float v = 0.f;
  for (int i = t; i < NN; i += 256) v += nll[i];
  s[t] = v; __syncthreads();
  for (int o = 128; o; o >>= 1){ if (t < o) s[t] += s[t + o]; __syncthreads(); }
  if (t == 0) out[0] = s[0] / (float)NN;
}

extern "C" void kernel_launch(void* const* d_in, const int* in_sizes, int n_in,
                              void* d_out, int out_size, void* d_ws, size_t ws_size,
                              hipStream_t stream) {
  const float* W   = (const float*)d_in[0];
  const float* ys  = (const float*)d_in[2];
  const int*   lab = (const int*)  d_in[3];
  const float* lam = (const float*)d_in[4];
  const float* ms  = (const float*)d_in[5];
  const float* mt  = (const float*)d_in[6];
  const float* CV  = (const float*)d_in[7];

  float* ws   = (float*)d_ws;
  float* tbl  = ws;                          // 4 x 40000 (quarter slabs, fully overwritten)
  float* accv = ws + 160000;                 // 256
  float* nll  = ws + 160256;                 // 1024
  _Float16* Whf = (_Float16*)(ws + 161280);  // 208*256 fp16
  float* out  = (float*)d_out;

  k_prep <<<53, 256, 0, stream>>>(W, lab, Whf, accv);
  dim3 gq(4, CC);
  k_quad <<<gq, 512, 0, stream>>>(Whf, CV, ms, mt, lam, tbl);
  k_rows <<<NN, 64, 0, stream>>>(ys, lab, accv, tbl, nll);
  k_mean <<<1, 256, 0, stream>>>(nll, out);
}